// Round 8
// baseline (1768.344 us; speedup 1.0000x reference)
//
#include <hip/hip_runtime.h>
#include <stdint.h>

#define N_NODES 50000
#define F_INF   128
#define T_P     12
#define N_EDGES 800000
#define MIDC    32

// ---------------- JAX Threefry-2x32 (20 rounds) ----------------
__device__ __forceinline__ uint32_t rotl32(uint32_t v, int r) {
  return (v << r) | (v >> (32 - r));
}

__device__ __forceinline__ void threefry(uint32_t k0, uint32_t k1,
                                         uint32_t x0, uint32_t x1,
                                         uint32_t& o0, uint32_t& o1) {
  uint32_t k2 = k0 ^ k1 ^ 0x1BD11BDAu;
  x0 += k0; x1 += k1;
#define TFR(r) { x0 += x1; x1 = rotl32(x1, r); x1 ^= x0; }
  TFR(13) TFR(15) TFR(26) TFR(6)
  x0 += k1; x1 += k2 + 1u;
  TFR(17) TFR(29) TFR(16) TFR(24)
  x0 += k2; x1 += k0 + 2u;
  TFR(13) TFR(15) TFR(26) TFR(6)
  x0 += k0; x1 += k1 + 3u;
  TFR(17) TFR(29) TFR(16) TFR(24)
  x0 += k1; x1 += k2 + 4u;
  TFR(13) TFR(15) TFR(26) TFR(6)
  x0 += k2; x1 += k0 + 5u;
#undef TFR
  o0 = x0; o1 = x1;
}

// JAX: uniform in [tiny,1) from top-23 mantissa bits, then gumbel = -log(-log(u))
__device__ __forceinline__ float gumbel_from_bits(uint32_t bits) {
  const float TINY = 1.17549435082228751e-38f;
  float f = __uint_as_float((bits >> 9) | 0x3F800000u) - 1.0f;
  float u = fmaxf(TINY, f * (1.0f - TINY) + TINY);
  return -logf(-logf(u));
}

// f32 -> bf16 bits, round-to-nearest-even
__device__ __forceinline__ uint16_t f2bf(float f) {
  uint32_t u = __float_as_uint(f);
  return (uint16_t)((u + 0x7FFFu + ((u >> 16) & 1u)) >> 16);
}
__device__ __forceinline__ float bf2f(uint16_t v) {
  return __uint_as_float(((uint32_t)v) << 16);
}

// f32 -> OCP e4m3fn (RNE, saturate to 448)
__device__ __forceinline__ uint32_t f2e4m3(float v) {
  float ax = fminf(fabsf(v), 448.0f);
  uint32_t s = (__float_as_uint(v) >> 31) << 7;
  uint32_t bits;
  if (ax < 0.015625f) {                    // denorm band: round(ax * 2^9)
    bits = (uint32_t)(int)rintf(ax * 512.0f);   // 0..8 (8 = first normal, correct)
  } else {
    uint32_t u = __float_as_uint(ax);
    u += 0x7FFFFu + ((u >> 20) & 1u);      // RNE at 3 mantissa bits
    uint32_t m = (u >> 20) & 7u;
    uint32_t E = (u >> 23) - 127u;
    bits = ((E + 7u) << 3) | m;
  }
  return s | bits;
}
__device__ __forceinline__ float e4m3f(uint32_t b) {
  uint32_t e = (b >> 3) & 15u, m = b & 7u;
  float mag = (e == 0) ? (float)m * 0.001953125f
                       : __uint_as_float(((e + 120u) << 23) | (m << 20));
  return (b & 0x80u) ? -mag : mag;
}

// Partitionable threefry (JAX >= 0.5 default):
//   split(key, n): subkey i = (o0, o1) of threefry(key, hi=0, lo=i)
//   random_bits(key, 32, shape): elem i = o0 ^ o1 of threefry(key, 0, i)
// header: [0..11] probs, [12] gmax, [13] inv_sum, uint slots 16,17 = subkey k2
__global__ void k_probs(const float* __restrict__ att, float* __restrict__ header) {
  if (threadIdx.x == 0) {
    uint32_t a0, a1, b0, b1;
    threefry(0u, 42u, 0u, 0u, a0, a1);   // k1 = split(key(42))[0]
    threefry(0u, 42u, 0u, 1u, b0, b1);   // k2 = split(key(42))[1]
    float v[12], m = -3.4e38f;
    for (int t = 0; t < 12; ++t) {
      uint32_t o0, o1;
      threefry(a0, a1, 0u, (uint32_t)t, o0, o1);
      v[t] = att[t] + gumbel_from_bits(o0 ^ o1);
      m = fmaxf(m, v[t]);
    }
    float s = 0.f;
    for (int t = 0; t < 12; ++t) { v[t] = expf(v[t] - m); s += v[t]; }
    for (int t = 0; t < 12; ++t) header[t] = v[t] / s;
    uint32_t* hu = (uint32_t*)header;
    hu[16] = b0; hu[17] = b1;
  }
}

// Wt[f*64 + cm] = (cm<32 ? W_l[cm][f] : W_r[cm-32][f])  (one-time transpose)
__global__ void k_wt(const float* __restrict__ Wl, const float* __restrict__ Wr,
                     float* __restrict__ wt) {
  int i = blockIdx.x * blockDim.x + threadIdx.x;
  if (i >= 64 * 128) return;
  int f = i >> 6, cm = i & 63;
  wt[i] = (cm < 32) ? Wl[cm * 128 + f] : Wr[(cm - 32) * 128 + f];
}

__global__ void k_deg(const int* __restrict__ dst, int* __restrict__ cnt) {
  int e = blockIdx.x * blockDim.x + threadIdx.x;
  if (e < N_EDGES) atomicAdd(&cnt[dst[e]], 1);
}

__global__ void k_scan(const int* __restrict__ cnt, int* __restrict__ rowptr) {
  __shared__ int sb[1024];
  int tid = threadIdx.x;
  const int chunk = (N_NODES + 1023) / 1024;
  int start = tid * chunk;
  int end   = min(start + chunk, N_NODES);
  int sum = 0;
  for (int i = start; i < end; ++i) sum += cnt[i];
  sb[tid] = sum;
  __syncthreads();
  for (int off = 1; off < 1024; off <<= 1) {
    int v = (tid >= off) ? sb[tid - off] : 0;
    __syncthreads();
    sb[tid] += v;
    __syncthreads();
  }
  int excl = sb[tid] - sum;
  int run = excl;
  for (int i = start; i < end; ++i) { rowptr[i] = run; run += cnt[i]; }
  if (tid == 1023) rowptr[N_NODES] = sb[1023];
}

__global__ void k_scatter(const int* __restrict__ src, const int* __restrict__ dst,
                          const int* __restrict__ rowptr, int* __restrict__ cursor,
                          int* __restrict__ col) {
  int e = blockIdx.x * blockDim.x + threadIdx.x;
  if (e < N_EDGES) {
    int d = dst[e];
    int pos = rowptr[d] + atomicAdd(&cursor[d], 1);
    col[pos] = src[e];
  }
}

// Block: 16 nodes. Lane group: 16 lanes/node, lane owns 4 channels cm=cs*4..+3
// (cm<32 -> Y fp8 path, else OUTI bf16 path). x and W streamed through small
// LDS buffers in 8-f chunks, software-pipelined via registers.
// Y[n][t*32+c]    = e4m3( x_nt . W_l[c] )
// OUTI[n][t*32+c] = bf16( (x_nt . W_r[c]) + b_l[c] )
#define XST 100   // 96 floats per node-chunk + 4 pad
__launch_bounds__(256, 4)
__global__ void k_project(const float* __restrict__ x, const float* __restrict__ wt,
                          const float* __restrict__ bl,
                          uint8_t* __restrict__ Y, uint16_t* __restrict__ OUTI) {
  __shared__ float Wb[512];          // one 8-f chunk of W: [f][64cm]
  __shared__ float xs[16 * XST];
  int tid = threadIdx.x;

  int node_base = blockIdx.x * 16;
  // staging role: 16 threads/node; thread loads float4 slot sl, plus 16+sl if sl<8
  int nl = tid >> 4, sl = tid & 15;
  bool valid = (node_base + nl) < N_NODES;
  bool has2  = valid && (sl < 8);
  const float4* src = reinterpret_cast<const float4*>(
      x + (size_t)(node_base + nl) * (F_INF * T_P));
  const float2* wsrc = reinterpret_cast<const float2*>(wt);
  // compute role: 4 node-groups of 16 lanes per wave
  int wid = tid >> 6, lane = tid & 63;
  int nlc = wid * 4 + (lane >> 4), cs = lane & 15;

  float4 acc[12];
#pragma unroll
  for (int t = 0; t < 12; ++t) acc[t] = make_float4(0.f, 0.f, 0.f, 0.f);

  float4 r0, r1;
  float2 rw;
  // chunk 0 load
  if (valid) { r0 = src[sl]; }
  if (has2)  { r1 = src[16 + sl]; }
  rw = wsrc[tid];
  // write chunk 0
  if (valid) *reinterpret_cast<float4*>(&xs[nl * XST + sl * 4]) = r0;
  if (has2)  *reinterpret_cast<float4*>(&xs[nl * XST + (16 + sl) * 4]) = r1;
  *reinterpret_cast<float2*>(&Wb[tid * 2]) = rw;
  // prefetch chunk 1
  if (valid) { r0 = src[24 + sl]; }
  if (has2)  { r1 = src[24 + 16 + sl]; }
  rw = wsrc[256 + tid];
  __syncthreads();

#pragma unroll 1
  for (int ch = 0; ch < 16; ++ch) {
#pragma unroll
    for (int f = 0; f < 8; ++f) {
      float4 w0 = *reinterpret_cast<const float4*>(&Wb[f * 64 + cs * 4]);
      const float* xp = &xs[nlc * XST + f * 12];
#pragma unroll
      for (int g = 0; g < 3; ++g) {
        float4 xv = *reinterpret_cast<const float4*>(xp + g * 4);
        int tb = g * 4;
        acc[tb+0].x += w0.x * xv.x; acc[tb+0].y += w0.y * xv.x;
        acc[tb+0].z += w0.z * xv.x; acc[tb+0].w += w0.w * xv.x;
        acc[tb+1].x += w0.x * xv.y; acc[tb+1].y += w0.y * xv.y;
        acc[tb+1].z += w0.z * xv.y; acc[tb+1].w += w0.w * xv.y;
        acc[tb+2].x += w0.x * xv.z; acc[tb+2].y += w0.y * xv.z;
        acc[tb+2].z += w0.z * xv.z; acc[tb+2].w += w0.w * xv.z;
        acc[tb+3].x += w0.x * xv.w; acc[tb+3].y += w0.y * xv.w;
        acc[tb+3].z += w0.z * xv.w; acc[tb+3].w += w0.w * xv.w;
      }
    }
    if (ch < 15) {
      __syncthreads();           // everyone done reading xs/Wb
      if (valid) *reinterpret_cast<float4*>(&xs[nl * XST + sl * 4]) = r0;
      if (has2)  *reinterpret_cast<float4*>(&xs[nl * XST + (16 + sl) * 4]) = r1;
      *reinterpret_cast<float2*>(&Wb[tid * 2]) = rw;
      if (ch < 14) {             // prefetch chunk ch+2
        int b = (ch + 2) * 24;
        if (valid) { r0 = src[b + sl]; }
        if (has2)  { r1 = src[b + 16 + sl]; }
        rw = wsrc[(ch + 2) * 256 + tid];
      }
      __syncthreads();           // chunk ch+1 ready
    }
  }

  int node = node_base + nlc;
  if (node >= N_NODES) return;
  int cm0 = cs * 4;
  if (cm0 < 32) {
    uint8_t* d = Y + (size_t)node * 384 + cm0;
#pragma unroll
    for (int t = 0; t < 12; ++t) {
      float* a = &acc[t].x;
      uint32_t p = 0;
#pragma unroll
      for (int k = 0; k < 4; ++k) p |= f2e4m3(a[k]) << (8 * k);
      *reinterpret_cast<uint32_t*>(d + t * 32) = p;
    }
  } else {
    int c0 = cm0 - 32;
    float4 bb = *reinterpret_cast<const float4*>(&bl[c0]);
    uint16_t* d = OUTI + (size_t)node * 384 + c0;
#pragma unroll
    for (int t = 0; t < 12; ++t) {
      ushort4 a;
      a.x = f2bf(acc[t].x + bb.x); a.y = f2bf(acc[t].y + bb.y);
      a.z = f2bf(acc[t].z + bb.z); a.w = f2bf(acc[t].w + bb.w);
      *reinterpret_cast<ushort4*>(d + t * 32) = a;
    }
  }
}

// per node: sum fp8 Y over CSR neighbors, *inv_deg, + bf16 OUTI, L2-normalize
// per t, h = sum_t probs[t]*out_t, leaky, dot lin_W, + lin_b + g2(n) -> s[n]
__global__ void k_gather(const uint8_t* __restrict__ Y, const uint16_t* __restrict__ OUTI,
                         const int* __restrict__ rowptr, const int* __restrict__ col,
                         const float* __restrict__ header,
                         const float* __restrict__ linW, const float* __restrict__ linb,
                         float* __restrict__ sout) {
  int n = blockIdx.x;
  int tid = threadIdx.x;         // 0..383
  int t = tid >> 5, c = tid & 31;
  int beg = rowptr[n], end = rowptr[n + 1];
  float acc = 0.f;
  int j = beg;
  for (; j + 3 < end; j += 4) {
    int s0 = col[j], s1 = col[j + 1], s2 = col[j + 2], s3 = col[j + 3];
    uint32_t b0 = Y[(size_t)s0 * 384 + tid];
    uint32_t b1 = Y[(size_t)s1 * 384 + tid];
    uint32_t b2 = Y[(size_t)s2 * 384 + tid];
    uint32_t b3 = Y[(size_t)s3 * 384 + tid];
    acc += e4m3f(b0) + e4m3f(b1) + e4m3f(b2) + e4m3f(b3);
  }
  for (; j < end; ++j) acc += e4m3f(Y[(size_t)col[j] * 384 + tid]);
  float invd = 1.0f / fmaxf((float)(end - beg), 1.0f);
  float val = bf2f(OUTI[(size_t)n * 384 + tid]) + acc * invd;
  float sq = val * val;
#pragma unroll
  for (int m = 16; m >= 1; m >>= 1) sq += __shfl_xor(sq, m, 64);
  float nv = val / fmaxf(sqrtf(sq), 1e-12f);
  float contrib = header[t] * nv;
  __shared__ float hb[12][32];
  hb[t][c] = contrib;
  __syncthreads();
  if (tid < 32) {
    float h = 0.f;
#pragma unroll
    for (int tt = 0; tt < 12; ++tt) h += hb[tt][tid];
    h = (h > 0.f) ? h : 0.01f * h;
    float hv = h * linW[tid];
#pragma unroll
    for (int m = 16; m >= 1; m >>= 1) hv += __shfl_xor(hv, m, 64);
    if (tid == 0) {
      const uint32_t* hu = (const uint32_t*)header;
      uint32_t o0, o1;
      threefry(hu[16], hu[17], 0u, (uint32_t)n, o0, o1);
      sout[n] = hv + linb[0] + gumbel_from_bits(o0 ^ o1);
    }
  }
}

__global__ void k_pmax(const float* __restrict__ s, float* __restrict__ pmax) {
  __shared__ float sb[256];
  float m = -3.4e38f;
  for (int i = blockIdx.x * 256 + threadIdx.x; i < N_NODES; i += 64 * 256)
    m = fmaxf(m, s[i]);
  sb[threadIdx.x] = m;
  __syncthreads();
  for (int o = 128; o > 0; o >>= 1) {
    if (threadIdx.x < o) sb[threadIdx.x] = fmaxf(sb[threadIdx.x], sb[threadIdx.x + o]);
    __syncthreads();
  }
  if (threadIdx.x == 0) pmax[blockIdx.x] = sb[0];
}

__global__ void k_fmax(const float* __restrict__ pmax, float* __restrict__ header) {
  float m = pmax[threadIdx.x];
#pragma unroll
  for (int o = 32; o >= 1; o >>= 1) m = fmaxf(m, __shfl_xor(m, o, 64));
  if (threadIdx.x == 0) header[12] = m;
}

__global__ void k_exps(const float* __restrict__ s, const float* __restrict__ header,
                       float* __restrict__ out, float* __restrict__ psum) {
  __shared__ float sb[256];
  float gm = header[12];
  float acc = 0.f;
  for (int i = blockIdx.x * 256 + threadIdx.x; i < N_NODES; i += 64 * 256) {
    float e = expf(s[i] - gm);
    out[i] = e;
    acc += e;
  }
  sb[threadIdx.x] = acc;
  __syncthreads();
  for (int o = 128; o > 0; o >>= 1) {
    if (threadIdx.x < o) sb[threadIdx.x] += sb[threadIdx.x + o];
    __syncthreads();
  }
  if (threadIdx.x == 0) psum[blockIdx.x] = sb[0];
}

__global__ void k_fsum(const float* __restrict__ psum, float* __restrict__ header) {
  float v = psum[threadIdx.x];
#pragma unroll
  for (int o = 32; o >= 1; o >>= 1) v += __shfl_xor(v, o, 64);
  if (threadIdx.x == 0) header[13] = 1.0f / v;
}

__global__ void k_scale(float* __restrict__ out, const float* __restrict__ header) {
  int i = blockIdx.x * blockDim.x + threadIdx.x;
  if (i < N_NODES) out[i] *= header[13];
}

extern "C" void kernel_launch(void* const* d_in, const int* in_sizes, int n_in,
                              void* d_out, int out_size, void* d_ws, size_t ws_size,
                              hipStream_t stream) {
  (void)in_sizes; (void)n_in; (void)out_size; (void)ws_size;
  const float* x    = (const float*)d_in[0];
  const int*   ei   = (const int*)d_in[1];   // int per harness convention
  const float* Wl   = (const float*)d_in[3];
  const float* bl   = (const float*)d_in[4];
  const float* Wr   = (const float*)d_in[5];
  const float* att  = (const float*)d_in[6];
  const float* linW = (const float*)d_in[7];
  const float* linb = (const float*)d_in[8];
  float* out = (float*)d_out;

  const int* esrc = ei;
  const int* edst = ei + N_EDGES;

  char* base = (char*)d_ws;
  size_t o = 0;
  auto take = [&](size_t b) { size_t r = o; o += (b + 255) & ~(size_t)255; return r; };
  float* header = (float*)(base + take(256));
  int*   cnt    = (int*)(base + take((size_t)N_NODES * 4));
  int*   cursor = (int*)(base + take((size_t)N_NODES * 4));
  int*   rowptr = (int*)(base + take((size_t)(N_NODES + 1) * 4));
  int*   col    = (int*)(base + take((size_t)N_EDGES * 4));
  float* sbuf   = (float*)(base + take((size_t)N_NODES * 4));
  float* pmax   = (float*)(base + take(64 * 4));
  float* psum   = (float*)(base + take(64 * 4));
  float* wt     = (float*)(base + take(64 * 128 * 4));
  uint8_t*  Y   = (uint8_t*)(base + take((size_t)N_NODES * 384));
  uint16_t* OUTI= (uint16_t*)(base + take((size_t)N_NODES * 384 * 2));

  hipMemsetAsync(cnt, 0, (size_t)N_NODES * 4, stream);
  hipMemsetAsync(cursor, 0, (size_t)N_NODES * 4, stream);

  k_probs<<<1, 64, 0, stream>>>(att, header);
  k_wt<<<(64 * 128 + 255) / 256, 256, 0, stream>>>(Wl, Wr, wt);
  k_deg<<<(N_EDGES + 255) / 256, 256, 0, stream>>>(edst, cnt);
  k_scan<<<1, 1024, 0, stream>>>(cnt, rowptr);
  k_scatter<<<(N_EDGES + 255) / 256, 256, 0, stream>>>(esrc, edst, rowptr, cursor, col);
  k_project<<<(N_NODES + 15) / 16, 256, 0, stream>>>(x, wt, bl, Y, OUTI);
  k_gather<<<N_NODES, 384, 0, stream>>>(Y, OUTI, rowptr, col, header, linW, linb, sbuf);
  k_pmax<<<64, 256, 0, stream>>>(sbuf, pmax);
  k_fmax<<<1, 64, 0, stream>>>(pmax, header);
  k_exps<<<64, 256, 0, stream>>>(sbuf, header, out, psum);
  k_fsum<<<1, 64, 0, stream>>>(psum, header);
  k_scale<<<(N_NODES + 255) / 256, 256, 0, stream>>>(out, header);
}

// Round 9
// 542.809 us; speedup vs baseline: 3.2578x; 3.2578x over previous
//
#include <hip/hip_runtime.h>
#include <stdint.h>

#define N_NODES 50000
#define F_INF   128
#define T_P     12
#define N_EDGES 800000
#define MIDC    32

// ---------------- JAX Threefry-2x32 (20 rounds) ----------------
__device__ __forceinline__ uint32_t rotl32(uint32_t v, int r) {
  return (v << r) | (v >> (32 - r));
}

__device__ __forceinline__ void threefry(uint32_t k0, uint32_t k1,
                                         uint32_t x0, uint32_t x1,
                                         uint32_t& o0, uint32_t& o1) {
  uint32_t k2 = k0 ^ k1 ^ 0x1BD11BDAu;
  x0 += k0; x1 += k1;
#define TFR(r) { x0 += x1; x1 = rotl32(x1, r); x1 ^= x0; }
  TFR(13) TFR(15) TFR(26) TFR(6)
  x0 += k1; x1 += k2 + 1u;
  TFR(17) TFR(29) TFR(16) TFR(24)
  x0 += k2; x1 += k0 + 2u;
  TFR(13) TFR(15) TFR(26) TFR(6)
  x0 += k0; x1 += k1 + 3u;
  TFR(17) TFR(29) TFR(16) TFR(24)
  x0 += k1; x1 += k2 + 4u;
  TFR(13) TFR(15) TFR(26) TFR(6)
  x0 += k2; x1 += k0 + 5u;
#undef TFR
  o0 = x0; o1 = x1;
}

// JAX: uniform in [tiny,1) from top-23 mantissa bits, then gumbel = -log(-log(u))
__device__ __forceinline__ float gumbel_from_bits(uint32_t bits) {
  const float TINY = 1.17549435082228751e-38f;
  float f = __uint_as_float((bits >> 9) | 0x3F800000u) - 1.0f;
  float u = fmaxf(TINY, f * (1.0f - TINY) + TINY);
  return -logf(-logf(u));
}

// f32 -> bf16 bits, round-to-nearest-even
__device__ __forceinline__ uint16_t f2bf(float f) {
  uint32_t u = __float_as_uint(f);
  return (uint16_t)((u + 0x7FFFu + ((u >> 16) & 1u)) >> 16);
}
__device__ __forceinline__ float bf2f(uint16_t v) {
  return __uint_as_float(((uint32_t)v) << 16);
}

// f32 -> OCP e4m3fn (RNE, saturate to 448)
__device__ __forceinline__ uint32_t f2e4m3(float v) {
  float ax = fminf(fabsf(v), 448.0f);
  uint32_t s = (__float_as_uint(v) >> 31) << 7;
  uint32_t bits;
  if (ax < 0.015625f) {                    // denorm band: round(ax * 2^9)
    bits = (uint32_t)(int)rintf(ax * 512.0f);   // 0..8 (8 = first normal, correct)
  } else {
    uint32_t u = __float_as_uint(ax);
    u += 0x7FFFFu + ((u >> 20) & 1u);      // RNE at 3 mantissa bits
    uint32_t m = (u >> 20) & 7u;
    uint32_t E = (u >> 23) - 127u;
    bits = ((E + 7u) << 3) | m;
  }
  return s | bits;
}
__device__ __forceinline__ float e4m3f(uint32_t b) {
  uint32_t e = (b >> 3) & 15u, m = b & 7u;
  float mag = (e == 0) ? (float)m * 0.001953125f
                       : __uint_as_float(((e + 120u) << 23) | (m << 20));
  return (b & 0x80u) ? -mag : mag;
}

// Partitionable threefry (JAX >= 0.5 default):
//   split(key, n): subkey i = (o0, o1) of threefry(key, hi=0, lo=i)
//   random_bits(key, 32, shape): elem i = o0 ^ o1 of threefry(key, 0, i)
// header: [0..11] probs, [12] gmax, [13] inv_sum, uint slots 16,17 = subkey k2
__global__ void k_probs(const float* __restrict__ att, float* __restrict__ header) {
  if (threadIdx.x == 0) {
    uint32_t a0, a1, b0, b1;
    threefry(0u, 42u, 0u, 0u, a0, a1);   // k1 = split(key(42))[0]
    threefry(0u, 42u, 0u, 1u, b0, b1);   // k2 = split(key(42))[1]
    float v[12], m = -3.4e38f;
    for (int t = 0; t < 12; ++t) {
      uint32_t o0, o1;
      threefry(a0, a1, 0u, (uint32_t)t, o0, o1);
      v[t] = att[t] + gumbel_from_bits(o0 ^ o1);
      m = fmaxf(m, v[t]);
    }
    float s = 0.f;
    for (int t = 0; t < 12; ++t) { v[t] = expf(v[t] - m); s += v[t]; }
    for (int t = 0; t < 12; ++t) header[t] = v[t] / s;
    uint32_t* hu = (uint32_t*)header;
    hu[16] = b0; hu[17] = b1;
  }
}

// Wt[f*64 + cm] = (cm<32 ? W_l[cm][f] : W_r[cm-32][f])  (one-time transpose)
__global__ void k_wt(const float* __restrict__ Wl, const float* __restrict__ Wr,
                     float* __restrict__ wt) {
  int i = blockIdx.x * blockDim.x + threadIdx.x;
  if (i >= 64 * 128) return;
  int f = i >> 6, cm = i & 63;
  wt[i] = (cm < 32) ? Wl[cm * 128 + f] : Wr[(cm - 32) * 128 + f];
}

__global__ void k_deg(const int* __restrict__ dst, int* __restrict__ cnt) {
  int e = blockIdx.x * blockDim.x + threadIdx.x;
  if (e < N_EDGES) atomicAdd(&cnt[dst[e]], 1);
}

__global__ void k_scan(const int* __restrict__ cnt, int* __restrict__ rowptr) {
  __shared__ int sb[1024];
  int tid = threadIdx.x;
  const int chunk = (N_NODES + 1023) / 1024;
  int start = tid * chunk;
  int end   = min(start + chunk, N_NODES);
  int sum = 0;
  for (int i = start; i < end; ++i) sum += cnt[i];
  sb[tid] = sum;
  __syncthreads();
  for (int off = 1; off < 1024; off <<= 1) {
    int v = (tid >= off) ? sb[tid - off] : 0;
    __syncthreads();
    sb[tid] += v;
    __syncthreads();
  }
  int excl = sb[tid] - sum;
  int run = excl;
  for (int i = start; i < end; ++i) { rowptr[i] = run; run += cnt[i]; }
  if (tid == 1023) rowptr[N_NODES] = sb[1023];
}

__global__ void k_scatter(const int* __restrict__ src, const int* __restrict__ dst,
                          const int* __restrict__ rowptr, int* __restrict__ cursor,
                          int* __restrict__ col) {
  int e = blockIdx.x * blockDim.x + threadIdx.x;
  if (e < N_EDGES) {
    int d = dst[e];
    int pos = rowptr[d] + atomicAdd(&cursor[d], 1);
    col[pos] = src[e];
  }
}

// Block: 16 nodes. Lane group: 16 lanes/node, lane owns 4 channels cm=cs*4..+3
// (cm<32 -> Y fp8 path, else OUTI bf16 path). x and W streamed through small
// LDS buffers in 8-f chunks, software-pipelined via registers.
// Y[n][t*32+c]    = e4m3( x_nt . W_l[c] )
// OUTI[n][t*32+c] = bf16( (x_nt . W_r[c]) + b_l[c] )
#define XST 100   // 96 floats per node-chunk + 4 pad
__launch_bounds__(256)
__global__ void k_project(const float* __restrict__ x, const float* __restrict__ wt,
                          const float* __restrict__ bl,
                          uint8_t* __restrict__ Y, uint16_t* __restrict__ OUTI) {
  __shared__ float Wb[512];          // one 8-f chunk of W: [f][64cm]
  __shared__ float xs[16 * XST];
  int tid = threadIdx.x;

  int node_base = blockIdx.x * 16;
  // staging role: 16 threads/node; thread loads float4 slot sl, plus 16+sl if sl<8
  int nl = tid >> 4, sl = tid & 15;
  bool valid = (node_base + nl) < N_NODES;
  bool has2  = valid && (sl < 8);
  const float4* src = reinterpret_cast<const float4*>(
      x + (size_t)(node_base + nl) * (F_INF * T_P));
  const float2* wsrc = reinterpret_cast<const float2*>(wt);
  // compute role: 4 node-groups of 16 lanes per wave
  int wid = tid >> 6, lane = tid & 63;
  int nlc = wid * 4 + (lane >> 4), cs = lane & 15;

  float4 acc[12];
#pragma unroll
  for (int t = 0; t < 12; ++t) acc[t] = make_float4(0.f, 0.f, 0.f, 0.f);

  float4 r0, r1;
  float2 rw;
  // chunk 0 load
  if (valid) { r0 = src[sl]; }
  if (has2)  { r1 = src[16 + sl]; }
  rw = wsrc[tid];
  // write chunk 0
  if (valid) *reinterpret_cast<float4*>(&xs[nl * XST + sl * 4]) = r0;
  if (has2)  *reinterpret_cast<float4*>(&xs[nl * XST + (16 + sl) * 4]) = r1;
  *reinterpret_cast<float2*>(&Wb[tid * 2]) = rw;
  // prefetch chunk 1
  if (valid) { r0 = src[24 + sl]; }
  if (has2)  { r1 = src[24 + 16 + sl]; }
  rw = wsrc[256 + tid];
  __syncthreads();

#pragma unroll 1
  for (int ch = 0; ch < 16; ++ch) {
#pragma unroll
    for (int f = 0; f < 8; ++f) {
      float4 w0 = *reinterpret_cast<const float4*>(&Wb[f * 64 + cs * 4]);
      const float* xp = &xs[nlc * XST + f * 12];
#pragma unroll
      for (int g = 0; g < 3; ++g) {
        float4 xv = *reinterpret_cast<const float4*>(xp + g * 4);
        int tb = g * 4;
        acc[tb+0].x += w0.x * xv.x; acc[tb+0].y += w0.y * xv.x;
        acc[tb+0].z += w0.z * xv.x; acc[tb+0].w += w0.w * xv.x;
        acc[tb+1].x += w0.x * xv.y; acc[tb+1].y += w0.y * xv.y;
        acc[tb+1].z += w0.z * xv.y; acc[tb+1].w += w0.w * xv.y;
        acc[tb+2].x += w0.x * xv.z; acc[tb+2].y += w0.y * xv.z;
        acc[tb+2].z += w0.z * xv.z; acc[tb+2].w += w0.w * xv.z;
        acc[tb+3].x += w0.x * xv.w; acc[tb+3].y += w0.y * xv.w;
        acc[tb+3].z += w0.z * xv.w; acc[tb+3].w += w0.w * xv.w;
      }
    }
    if (ch < 15) {
      __syncthreads();           // everyone done reading xs/Wb
      if (valid) *reinterpret_cast<float4*>(&xs[nl * XST + sl * 4]) = r0;
      if (has2)  *reinterpret_cast<float4*>(&xs[nl * XST + (16 + sl) * 4]) = r1;
      *reinterpret_cast<float2*>(&Wb[tid * 2]) = rw;
      if (ch < 14) {             // prefetch chunk ch+2
        int b = (ch + 2) * 24;
        if (valid) { r0 = src[b + sl]; }
        if (has2)  { r1 = src[b + 16 + sl]; }
        rw = wsrc[(ch + 2) * 256 + tid];
      }
      __syncthreads();           // chunk ch+1 ready
    }
  }

  int node = node_base + nlc;
  if (node >= N_NODES) return;
  int cm0 = cs * 4;
  if (cm0 < 32) {
    uint8_t* d = Y + (size_t)node * 384 + cm0;
#pragma unroll
    for (int t = 0; t < 12; ++t) {
      float* a = &acc[t].x;
      uint32_t p = 0;
#pragma unroll
      for (int k = 0; k < 4; ++k) p |= f2e4m3(a[k]) << (8 * k);
      *reinterpret_cast<uint32_t*>(d + t * 32) = p;
    }
  } else {
    int c0 = cm0 - 32;
    float4 bb = *reinterpret_cast<const float4*>(&bl[c0]);
    uint16_t* d = OUTI + (size_t)node * 384 + c0;
#pragma unroll
    for (int t = 0; t < 12; ++t) {
      ushort4 a;
      a.x = f2bf(acc[t].x + bb.x); a.y = f2bf(acc[t].y + bb.y);
      a.z = f2bf(acc[t].z + bb.z); a.w = f2bf(acc[t].w + bb.w);
      *reinterpret_cast<ushort4*>(d + t * 32) = a;
    }
  }
}

// per node: sum fp8 Y over CSR neighbors, *inv_deg, + bf16 OUTI, L2-normalize
// per t, h = sum_t probs[t]*out_t, leaky, dot lin_W, + lin_b + g2(n) -> s[n]
__global__ void k_gather(const uint8_t* __restrict__ Y, const uint16_t* __restrict__ OUTI,
                         const int* __restrict__ rowptr, const int* __restrict__ col,
                         const float* __restrict__ header,
                         const float* __restrict__ linW, const float* __restrict__ linb,
                         float* __restrict__ sout) {
  int n = blockIdx.x;
  int tid = threadIdx.x;         // 0..383
  int t = tid >> 5, c = tid & 31;
  int beg = rowptr[n], end = rowptr[n + 1];
  float acc = 0.f;
  int j = beg;
  for (; j + 3 < end; j += 4) {
    int s0 = col[j], s1 = col[j + 1], s2 = col[j + 2], s3 = col[j + 3];
    uint32_t b0 = Y[(size_t)s0 * 384 + tid];
    uint32_t b1 = Y[(size_t)s1 * 384 + tid];
    uint32_t b2 = Y[(size_t)s2 * 384 + tid];
    uint32_t b3 = Y[(size_t)s3 * 384 + tid];
    acc += e4m3f(b0) + e4m3f(b1) + e4m3f(b2) + e4m3f(b3);
  }
  for (; j < end; ++j) acc += e4m3f(Y[(size_t)col[j] * 384 + tid]);
  float invd = 1.0f / fmaxf((float)(end - beg), 1.0f);
  float val = bf2f(OUTI[(size_t)n * 384 + tid]) + acc * invd;
  float sq = val * val;
#pragma unroll
  for (int m = 16; m >= 1; m >>= 1) sq += __shfl_xor(sq, m, 64);
  float nv = val / fmaxf(sqrtf(sq), 1e-12f);
  float contrib = header[t] * nv;
  __shared__ float hb[12][32];
  hb[t][c] = contrib;
  __syncthreads();
  if (tid < 32) {
    float h = 0.f;
#pragma unroll
    for (int tt = 0; tt < 12; ++tt) h += hb[tt][tid];
    h = (h > 0.f) ? h : 0.01f * h;
    float hv = h * linW[tid];
#pragma unroll
    for (int m = 16; m >= 1; m >>= 1) hv += __shfl_xor(hv, m, 64);
    if (tid == 0) {
      const uint32_t* hu = (const uint32_t*)header;
      uint32_t o0, o1;
      threefry(hu[16], hu[17], 0u, (uint32_t)n, o0, o1);
      sout[n] = hv + linb[0] + gumbel_from_bits(o0 ^ o1);
    }
  }
}

__global__ void k_pmax(const float* __restrict__ s, float* __restrict__ pmax) {
  __shared__ float sb[256];
  float m = -3.4e38f;
  for (int i = blockIdx.x * 256 + threadIdx.x; i < N_NODES; i += 64 * 256)
    m = fmaxf(m, s[i]);
  sb[threadIdx.x] = m;
  __syncthreads();
  for (int o = 128; o > 0; o >>= 1) {
    if (threadIdx.x < o) sb[threadIdx.x] = fmaxf(sb[threadIdx.x], sb[threadIdx.x + o]);
    __syncthreads();
  }
  if (threadIdx.x == 0) pmax[blockIdx.x] = sb[0];
}

__global__ void k_fmax(const float* __restrict__ pmax, float* __restrict__ header) {
  float m = pmax[threadIdx.x];
#pragma unroll
  for (int o = 32; o >= 1; o >>= 1) m = fmaxf(m, __shfl_xor(m, o, 64));
  if (threadIdx.x == 0) header[12] = m;
}

__global__ void k_exps(const float* __restrict__ s, const float* __restrict__ header,
                       float* __restrict__ out, float* __restrict__ psum) {
  __shared__ float sb[256];
  float gm = header[12];
  float acc = 0.f;
  for (int i = blockIdx.x * 256 + threadIdx.x; i < N_NODES; i += 64 * 256) {
    float e = expf(s[i] - gm);
    out[i] = e;
    acc += e;
  }
  sb[threadIdx.x] = acc;
  __syncthreads();
  for (int o = 128; o > 0; o >>= 1) {
    if (threadIdx.x < o) sb[threadIdx.x] += sb[threadIdx.x + o];
    __syncthreads();
  }
  if (threadIdx.x == 0) psum[blockIdx.x] = sb[0];
}

__global__ void k_fsum(const float* __restrict__ psum, float* __restrict__ header) {
  float v = psum[threadIdx.x];
#pragma unroll
  for (int o = 32; o >= 1; o >>= 1) v += __shfl_xor(v, o, 64);
  if (threadIdx.x == 0) header[13] = 1.0f / v;
}

__global__ void k_scale(float* __restrict__ out, const float* __restrict__ header) {
  int i = blockIdx.x * blockDim.x + threadIdx.x;
  if (i < N_NODES) out[i] *= header[13];
}

extern "C" void kernel_launch(void* const* d_in, const int* in_sizes, int n_in,
                              void* d_out, int out_size, void* d_ws, size_t ws_size,
                              hipStream_t stream) {
  (void)in_sizes; (void)n_in; (void)out_size; (void)ws_size;
  const float* x    = (const float*)d_in[0];
  const int*   ei   = (const int*)d_in[1];   // int per harness convention
  const float* Wl   = (const float*)d_in[3];
  const float* bl   = (const float*)d_in[4];
  const float* Wr   = (const float*)d_in[5];
  const float* att  = (const float*)d_in[6];
  const float* linW = (const float*)d_in[7];
  const float* linb = (const float*)d_in[8];
  float* out = (float*)d_out;

  const int* esrc = ei;
  const int* edst = ei + N_EDGES;

  char* base = (char*)d_ws;
  size_t o = 0;
  auto take = [&](size_t b) { size_t r = o; o += (b + 255) & ~(size_t)255; return r; };
  float* header = (float*)(base + take(256));
  int*   cnt    = (int*)(base + take((size_t)N_NODES * 4));
  int*   cursor = (int*)(base + take((size_t)N_NODES * 4));
  int*   rowptr = (int*)(base + take((size_t)(N_NODES + 1) * 4));
  int*   col    = (int*)(base + take((size_t)N_EDGES * 4));
  float* sbuf   = (float*)(base + take((size_t)N_NODES * 4));
  float* pmax   = (float*)(base + take(64 * 4));
  float* psum   = (float*)(base + take(64 * 4));
  float* wt     = (float*)(base + take(64 * 128 * 4));
  uint8_t*  Y   = (uint8_t*)(base + take((size_t)N_NODES * 384));
  uint16_t* OUTI= (uint16_t*)(base + take((size_t)N_NODES * 384 * 2));

  hipMemsetAsync(cnt, 0, (size_t)N_NODES * 4, stream);
  hipMemsetAsync(cursor, 0, (size_t)N_NODES * 4, stream);

  k_probs<<<1, 64, 0, stream>>>(att, header);
  k_wt<<<(64 * 128 + 255) / 256, 256, 0, stream>>>(Wl, Wr, wt);
  k_deg<<<(N_EDGES + 255) / 256, 256, 0, stream>>>(edst, cnt);
  k_scan<<<1, 1024, 0, stream>>>(cnt, rowptr);
  k_scatter<<<(N_EDGES + 255) / 256, 256, 0, stream>>>(esrc, edst, rowptr, cursor, col);
  k_project<<<(N_NODES + 15) / 16, 256, 0, stream>>>(x, wt, bl, Y, OUTI);
  k_gather<<<N_NODES, 384, 0, stream>>>(Y, OUTI, rowptr, col, header, linW, linb, sbuf);
  k_pmax<<<64, 256, 0, stream>>>(sbuf, pmax);
  k_fmax<<<1, 64, 0, stream>>>(pmax, header);
  k_exps<<<64, 256, 0, stream>>>(sbuf, header, out, psum);
  k_fsum<<<1, 64, 0, stream>>>(psum, header);
  k_scale<<<(N_NODES + 255) / 256, 256, 0, stream>>>(out, header);
}

// Round 10
// 419.449 us; speedup vs baseline: 4.2159x; 1.2941x over previous
//
#include <hip/hip_runtime.h>
#include <hip/hip_fp16.h>
#include <stdint.h>

#define N_NODES 50000
#define F_INF   128
#define T_P     12
#define N_EDGES 800000
#define MIDC    32

// ---------------- JAX Threefry-2x32 (20 rounds) ----------------
__device__ __forceinline__ uint32_t rotl32(uint32_t v, int r) {
  return (v << r) | (v >> (32 - r));
}

__device__ __forceinline__ void threefry(uint32_t k0, uint32_t k1,
                                         uint32_t x0, uint32_t x1,
                                         uint32_t& o0, uint32_t& o1) {
  uint32_t k2 = k0 ^ k1 ^ 0x1BD11BDAu;
  x0 += k0; x1 += k1;
#define TFR(r) { x0 += x1; x1 = rotl32(x1, r); x1 ^= x0; }
  TFR(13) TFR(15) TFR(26) TFR(6)
  x0 += k1; x1 += k2 + 1u;
  TFR(17) TFR(29) TFR(16) TFR(24)
  x0 += k2; x1 += k0 + 2u;
  TFR(13) TFR(15) TFR(26) TFR(6)
  x0 += k0; x1 += k1 + 3u;
  TFR(17) TFR(29) TFR(16) TFR(24)
  x0 += k1; x1 += k2 + 4u;
  TFR(13) TFR(15) TFR(26) TFR(6)
  x0 += k2; x1 += k0 + 5u;
#undef TFR
  o0 = x0; o1 = x1;
}

// JAX: uniform in [tiny,1) from top-23 mantissa bits, then gumbel = -log(-log(u))
__device__ __forceinline__ float gumbel_from_bits(uint32_t bits) {
  const float TINY = 1.17549435082228751e-38f;
  float f = __uint_as_float((bits >> 9) | 0x3F800000u) - 1.0f;
  float u = fmaxf(TINY, f * (1.0f - TINY) + TINY);
  return -logf(-logf(u));
}

// f32 -> bf16 bits, round-to-nearest-even
__device__ __forceinline__ uint16_t f2bf(float f) {
  uint32_t u = __float_as_uint(f);
  return (uint16_t)((u + 0x7FFFu + ((u >> 16) & 1u)) >> 16);
}
__device__ __forceinline__ float bf2f(uint16_t v) {
  return __uint_as_float(((uint32_t)v) << 16);
}

// f32 -> fp8 e5m2 (RNE, flush |v|<2^-14 to 0, saturate to 57344)
// e5m2 byte == high byte of the fp16 encoding.
__device__ __forceinline__ uint32_t f2e5m2(float v) {
  float ax = fabsf(v);
  uint32_t s = (__float_as_uint(v) >> 31) << 7;
  if (ax < 6.103515625e-5f) return s;          // flush denorms/zero
  ax = fminf(ax, 57344.0f);
  uint32_t u = __float_as_uint(ax);
  u += 0xFFFFFu + ((u >> 21) & 1u);            // RNE at 2 mantissa bits
  uint32_t m = (u >> 21) & 3u;
  uint32_t E = (u >> 23) - 127u + 15u;         // 5-bit exponent, bias 15
  return s | (E << 2) | m;
}
// e5m2 byte (in bits 8..15 of a u16) -> f32 via fp16 reinterpret
__device__ __forceinline__ float h16f(uint32_t hbits) {
  __half_raw r; r.x = (uint16_t)hbits;
  return __half2float(*reinterpret_cast<__half*>(&r));
}

// Partitionable threefry (JAX >= 0.5 default):
//   split(key, n): subkey i = (o0, o1) of threefry(key, hi=0, lo=i)
//   random_bits(key, 32, shape): elem i = o0 ^ o1 of threefry(key, 0, i)
// header: [0..11] probs, [12] gmax, [13] inv_sum, uint slots 16,17 = subkey k2
__global__ void k_probs(const float* __restrict__ att, float* __restrict__ header) {
  if (threadIdx.x == 0) {
    uint32_t a0, a1, b0, b1;
    threefry(0u, 42u, 0u, 0u, a0, a1);   // k1 = split(key(42))[0]
    threefry(0u, 42u, 0u, 1u, b0, b1);   // k2 = split(key(42))[1]
    float v[12], m = -3.4e38f;
    for (int t = 0; t < 12; ++t) {
      uint32_t o0, o1;
      threefry(a0, a1, 0u, (uint32_t)t, o0, o1);
      v[t] = att[t] + gumbel_from_bits(o0 ^ o1);
      m = fmaxf(m, v[t]);
    }
    float s = 0.f;
    for (int t = 0; t < 12; ++t) { v[t] = expf(v[t] - m); s += v[t]; }
    for (int t = 0; t < 12; ++t) header[t] = v[t] / s;
    uint32_t* hu = (uint32_t*)header;
    hu[16] = b0; hu[17] = b1;
  }
}

// Wt[f*64 + cm] = (cm<32 ? W_l[cm][f] : W_r[cm-32][f])  (one-time transpose)
__global__ void k_wt(const float* __restrict__ Wl, const float* __restrict__ Wr,
                     float* __restrict__ wt) {
  int i = blockIdx.x * blockDim.x + threadIdx.x;
  if (i >= 64 * 128) return;
  int f = i >> 6, cm = i & 63;
  wt[i] = (cm < 32) ? Wl[cm * 128 + f] : Wr[(cm - 32) * 128 + f];
}

__global__ void k_deg(const int* __restrict__ dst, int* __restrict__ cnt) {
  int e = blockIdx.x * blockDim.x + threadIdx.x;
  if (e < N_EDGES) atomicAdd(&cnt[dst[e]], 1);
}

__global__ void k_scan(const int* __restrict__ cnt, int* __restrict__ rowptr) {
  __shared__ int sb[1024];
  int tid = threadIdx.x;
  const int chunk = (N_NODES + 1023) / 1024;
  int start = tid * chunk;
  int end   = min(start + chunk, N_NODES);
  int sum = 0;
  for (int i = start; i < end; ++i) sum += cnt[i];
  sb[tid] = sum;
  __syncthreads();
  for (int off = 1; off < 1024; off <<= 1) {
    int v = (tid >= off) ? sb[tid - off] : 0;
    __syncthreads();
    sb[tid] += v;
    __syncthreads();
  }
  int excl = sb[tid] - sum;
  int run = excl;
  for (int i = start; i < end; ++i) { rowptr[i] = run; run += cnt[i]; }
  if (tid == 1023) rowptr[N_NODES] = sb[1023];
}

__global__ void k_scatter(const int* __restrict__ src, const int* __restrict__ dst,
                          const int* __restrict__ rowptr, int* __restrict__ cursor,
                          int* __restrict__ col) {
  int e = blockIdx.x * blockDim.x + threadIdx.x;
  if (e < N_EDGES) {
    int d = dst[e];
    int pos = rowptr[d] + atomicAdd(&cursor[d], 1);
    col[pos] = src[e];
  }
}

// Block: 16 nodes. Lane group: 16 lanes/node, lane owns 4 channels cm=cs*4..+3
// (cm<32 -> Y e5m2 path, else OUTI bf16 path). x and W streamed through small
// LDS buffers in 8-f chunks, software-pipelined via registers.
// Y[n][t*32+c]    = e5m2( x_nt . W_l[c] )
// OUTI[n][t*32+c] = bf16( (x_nt . W_r[c]) + b_l[c] )
#define XST 100   // 96 floats per node-chunk + 4 pad
__launch_bounds__(256)
__global__ void k_project(const float* __restrict__ x, const float* __restrict__ wt,
                          const float* __restrict__ bl,
                          uint8_t* __restrict__ Y, uint16_t* __restrict__ OUTI) {
  __shared__ float Wb[512];          // one 8-f chunk of W: [f][64cm]
  __shared__ float xs[16 * XST];
  int tid = threadIdx.x;

  int node_base = blockIdx.x * 16;
  // staging role: 16 threads/node; thread loads float4 slot sl, plus 16+sl if sl<8
  int nl = tid >> 4, sl = tid & 15;
  bool valid = (node_base + nl) < N_NODES;
  bool has2  = valid && (sl < 8);
  const float4* src = reinterpret_cast<const float4*>(
      x + (size_t)(node_base + nl) * (F_INF * T_P));
  const float2* wsrc = reinterpret_cast<const float2*>(wt);
  // compute role: 4 node-groups of 16 lanes per wave
  int wid = tid >> 6, lane = tid & 63;
  int nlc = wid * 4 + (lane >> 4), cs = lane & 15;

  float4 acc[12];
#pragma unroll
  for (int t = 0; t < 12; ++t) acc[t] = make_float4(0.f, 0.f, 0.f, 0.f);

  float4 r0, r1;
  float2 rw;
  // chunk 0 load
  if (valid) { r0 = src[sl]; }
  if (has2)  { r1 = src[16 + sl]; }
  rw = wsrc[tid];
  // write chunk 0
  if (valid) *reinterpret_cast<float4*>(&xs[nl * XST + sl * 4]) = r0;
  if (has2)  *reinterpret_cast<float4*>(&xs[nl * XST + (16 + sl) * 4]) = r1;
  *reinterpret_cast<float2*>(&Wb[tid * 2]) = rw;
  // prefetch chunk 1
  if (valid) { r0 = src[24 + sl]; }
  if (has2)  { r1 = src[24 + 16 + sl]; }
  rw = wsrc[256 + tid];
  __syncthreads();

#pragma unroll 1
  for (int ch = 0; ch < 16; ++ch) {
#pragma unroll
    for (int f = 0; f < 8; ++f) {
      float4 w0 = *reinterpret_cast<const float4*>(&Wb[f * 64 + cs * 4]);
      const float* xp = &xs[nlc * XST + f * 12];
#pragma unroll
      for (int g = 0; g < 3; ++g) {
        float4 xv = *reinterpret_cast<const float4*>(xp + g * 4);
        int tb = g * 4;
        acc[tb+0].x += w0.x * xv.x; acc[tb+0].y += w0.y * xv.x;
        acc[tb+0].z += w0.z * xv.x; acc[tb+0].w += w0.w * xv.x;
        acc[tb+1].x += w0.x * xv.y; acc[tb+1].y += w0.y * xv.y;
        acc[tb+1].z += w0.z * xv.y; acc[tb+1].w += w0.w * xv.y;
        acc[tb+2].x += w0.x * xv.z; acc[tb+2].y += w0.y * xv.z;
        acc[tb+2].z += w0.z * xv.z; acc[tb+2].w += w0.w * xv.z;
        acc[tb+3].x += w0.x * xv.w; acc[tb+3].y += w0.y * xv.w;
        acc[tb+3].z += w0.z * xv.w; acc[tb+3].w += w0.w * xv.w;
      }
    }
    if (ch < 15) {
      __syncthreads();           // everyone done reading xs/Wb
      if (valid) *reinterpret_cast<float4*>(&xs[nl * XST + sl * 4]) = r0;
      if (has2)  *reinterpret_cast<float4*>(&xs[nl * XST + (16 + sl) * 4]) = r1;
      *reinterpret_cast<float2*>(&Wb[tid * 2]) = rw;
      if (ch < 14) {             // prefetch chunk ch+2
        int b = (ch + 2) * 24;
        if (valid) { r0 = src[b + sl]; }
        if (has2)  { r1 = src[b + 16 + sl]; }
        rw = wsrc[(ch + 2) * 256 + tid];
      }
      __syncthreads();           // chunk ch+1 ready
    }
  }

  int node = node_base + nlc;
  if (node >= N_NODES) return;
  int cm0 = cs * 4;
  if (cm0 < 32) {
    uint8_t* d = Y + (size_t)node * 384 + cm0;
#pragma unroll
    for (int t = 0; t < 12; ++t) {
      float* a = &acc[t].x;
      uint32_t p = 0;
#pragma unroll
      for (int k = 0; k < 4; ++k) p |= f2e5m2(a[k]) << (8 * k);
      *reinterpret_cast<uint32_t*>(d + t * 32) = p;
    }
  } else {
    int c0 = cm0 - 32;
    float4 bb = *reinterpret_cast<const float4*>(&bl[c0]);
    uint16_t* d = OUTI + (size_t)node * 384 + c0;
#pragma unroll
    for (int t = 0; t < 12; ++t) {
      ushort4 a;
      a.x = f2bf(acc[t].x + bb.x); a.y = f2bf(acc[t].y + bb.y);
      a.z = f2bf(acc[t].z + bb.z); a.w = f2bf(acc[t].w + bb.w);
      *reinterpret_cast<ushort4*>(d + t * 32) = a;
    }
  }
}

// Block = 4 nodes x 96 threads. Thread owns 4 channels (one u32 of e5m2 Y per
// edge). Decode = byte-isolate + v_cvt_f32_f16. 8-thread groups (one t each)
// norm-reduce via shfl; h/lin epilogue on first 128 threads.
__launch_bounds__(384)
__global__ void k_gather(const uint8_t* __restrict__ Y, const uint16_t* __restrict__ OUTI,
                         const int* __restrict__ rowptr, const int* __restrict__ col,
                         const float* __restrict__ header,
                         const float* __restrict__ linW, const float* __restrict__ linb,
                         float* __restrict__ sout) {
  __shared__ float hb[4][12][33];
  int tid = threadIdx.x;         // 0..383
  int ln = tid / 96;             // node slot 0..3
  int tc = tid - ln * 96;        // u32-channel slot 0..95
  int n = blockIdx.x * 4 + ln;   // N_NODES % 4 == 0 -> always valid
  int t = tc >> 3, cq = tc & 7;  // t period; cq = channel quad within t

  int beg = rowptr[n], end = rowptr[n + 1];
  float a0 = 0.f, a1 = 0.f, a2 = 0.f, a3 = 0.f;
  const uint32_t* Yp = reinterpret_cast<const uint32_t*>(Y);
  int j = beg;
  for (; j + 3 < end; j += 4) {
    int s0 = col[j], s1 = col[j + 1], s2 = col[j + 2], s3 = col[j + 3];
    uint32_t u0 = Yp[(size_t)s0 * 96 + tc];
    uint32_t u1 = Yp[(size_t)s1 * 96 + tc];
    uint32_t u2 = Yp[(size_t)s2 * 96 + tc];
    uint32_t u3 = Yp[(size_t)s3 * 96 + tc];
    a0 += h16f(u0 << 8) + h16f(u1 << 8) + h16f(u2 << 8) + h16f(u3 << 8);
    a1 += h16f(u0 & 0xff00u) + h16f(u1 & 0xff00u) + h16f(u2 & 0xff00u) + h16f(u3 & 0xff00u);
    a2 += h16f((u0 >> 8) & 0xff00u) + h16f((u1 >> 8) & 0xff00u) +
          h16f((u2 >> 8) & 0xff00u) + h16f((u3 >> 8) & 0xff00u);
    a3 += h16f(u0 >> 16 & 0xff00u) + h16f(u1 >> 16 & 0xff00u) +
          h16f(u2 >> 16 & 0xff00u) + h16f(u3 >> 16 & 0xff00u);
  }
  for (; j < end; ++j) {
    uint32_t u = Yp[(size_t)col[j] * 96 + tc];
    a0 += h16f(u << 8);
    a1 += h16f(u & 0xff00u);
    a2 += h16f((u >> 8) & 0xff00u);
    a3 += h16f(u >> 16 & 0xff00u);
  }
  float invd = 1.0f / fmaxf((float)(end - beg), 1.0f);
  ushort4 ov = *reinterpret_cast<const ushort4*>(OUTI + (size_t)n * 384 + tc * 4);
  float v0 = bf2f(ov.x) + a0 * invd;
  float v1 = bf2f(ov.y) + a1 * invd;
  float v2 = bf2f(ov.z) + a2 * invd;
  float v3 = bf2f(ov.w) + a3 * invd;
  float sq = v0 * v0 + v1 * v1 + v2 * v2 + v3 * v3;
  sq += __shfl_xor(sq, 1);
  sq += __shfl_xor(sq, 2);
  sq += __shfl_xor(sq, 4);
  float rn = header[t] / fmaxf(sqrtf(sq), 1e-12f);
  float* hrow = &hb[ln][t][cq * 4];
  hrow[0] = v0 * rn; hrow[1] = v1 * rn; hrow[2] = v2 * rn; hrow[3] = v3 * rn;
  __syncthreads();
  if (tid < 128) {
    int ln2 = tid >> 5, c = tid & 31;
    float h = 0.f;
#pragma unroll
    for (int tt = 0; tt < 12; ++tt) h += hb[ln2][tt][c];
    h = (h > 0.f) ? h : 0.01f * h;
    float hv = h * linW[c];
#pragma unroll
    for (int m = 16; m >= 1; m >>= 1) hv += __shfl_xor(hv, m);
    if (c == 0) {
      int n2 = blockIdx.x * 4 + ln2;
      const uint32_t* hu = (const uint32_t*)header;
      uint32_t o0, o1;
      threefry(hu[16], hu[17], 0u, (uint32_t)n2, o0, o1);
      sout[n2] = hv + linb[0] + gumbel_from_bits(o0 ^ o1);
    }
  }
}

__global__ void k_pmax(const float* __restrict__ s, float* __restrict__ pmax) {
  __shared__ float sb[256];
  float m = -3.4e38f;
  for (int i = blockIdx.x * 256 + threadIdx.x; i < N_NODES; i += 64 * 256)
    m = fmaxf(m, s[i]);
  sb[threadIdx.x] = m;
  __syncthreads();
  for (int o = 128; o > 0; o >>= 1) {
    if (threadIdx.x < o) sb[threadIdx.x] = fmaxf(sb[threadIdx.x], sb[threadIdx.x + o]);
    __syncthreads();
  }
  if (threadIdx.x == 0) pmax[blockIdx.x] = sb[0];
}

__global__ void k_fmax(const float* __restrict__ pmax, float* __restrict__ header) {
  float m = pmax[threadIdx.x];
#pragma unroll
  for (int o = 32; o >= 1; o >>= 1) m = fmaxf(m, __shfl_xor(m, o, 64));
  if (threadIdx.x == 0) header[12] = m;
}

__global__ void k_exps(const float* __restrict__ s, const float* __restrict__ header,
                       float* __restrict__ out, float* __restrict__ psum) {
  __shared__ float sb[256];
  float gm = header[12];
  float acc = 0.f;
  for (int i = blockIdx.x * 256 + threadIdx.x; i < N_NODES; i += 64 * 256) {
    float e = expf(s[i] - gm);
    out[i] = e;
    acc += e;
  }
  sb[threadIdx.x] = acc;
  __syncthreads();
  for (int o = 128; o > 0; o >>= 1) {
    if (threadIdx.x < o) sb[threadIdx.x] += sb[threadIdx.x + o];
    __syncthreads();
  }
  if (threadIdx.x == 0) psum[blockIdx.x] = sb[0];
}

__global__ void k_fsum(const float* __restrict__ psum, float* __restrict__ header) {
  float v = psum[threadIdx.x];
#pragma unroll
  for (int o = 32; o >= 1; o >>= 1) v += __shfl_xor(v, o, 64);
  if (threadIdx.x == 0) header[13] = 1.0f / v;
}

__global__ void k_scale(float* __restrict__ out, const float* __restrict__ header) {
  int i = blockIdx.x * blockDim.x + threadIdx.x;
  if (i < N_NODES) out[i] *= header[13];
}

extern "C" void kernel_launch(void* const* d_in, const int* in_sizes, int n_in,
                              void* d_out, int out_size, void* d_ws, size_t ws_size,
                              hipStream_t stream) {
  (void)in_sizes; (void)n_in; (void)out_size; (void)ws_size;
  const float* x    = (const float*)d_in[0];
  const int*   ei   = (const int*)d_in[1];   // int per harness convention
  const float* Wl   = (const float*)d_in[3];
  const float* bl   = (const float*)d_in[4];
  const float* Wr   = (const float*)d_in[5];
  const float* att  = (const float*)d_in[6];
  const float* linW = (const float*)d_in[7];
  const float* linb = (const float*)d_in[8];
  float* out = (float*)d_out;

  const int* esrc = ei;
  const int* edst = ei + N_EDGES;

  char* base = (char*)d_ws;
  size_t o = 0;
  auto take = [&](size_t b) { size_t r = o; o += (b + 255) & ~(size_t)255; return r; };
  float* header = (float*)(base + take(256));
  int*   cnt    = (int*)(base + take((size_t)N_NODES * 4));
  int*   cursor = (int*)(base + take((size_t)N_NODES * 4));
  int*   rowptr = (int*)(base + take((size_t)(N_NODES + 1) * 4));
  int*   col    = (int*)(base + take((size_t)N_EDGES * 4));
  float* sbuf   = (float*)(base + take((size_t)N_NODES * 4));
  float* pmax   = (float*)(base + take(64 * 4));
  float* psum   = (float*)(base + take(64 * 4));
  float* wt     = (float*)(base + take(64 * 128 * 4));
  uint8_t*  Y   = (uint8_t*)(base + take((size_t)N_NODES * 384));
  uint16_t* OUTI= (uint16_t*)(base + take((size_t)N_NODES * 384 * 2));

  hipMemsetAsync(cnt, 0, (size_t)N_NODES * 4, stream);
  hipMemsetAsync(cursor, 0, (size_t)N_NODES * 4, stream);

  k_probs<<<1, 64, 0, stream>>>(att, header);
  k_wt<<<(64 * 128 + 255) / 256, 256, 0, stream>>>(Wl, Wr, wt);
  k_deg<<<(N_EDGES + 255) / 256, 256, 0, stream>>>(edst, cnt);
  k_scan<<<1, 1024, 0, stream>>>(cnt, rowptr);
  k_scatter<<<(N_EDGES + 255) / 256, 256, 0, stream>>>(esrc, edst, rowptr, cursor, col);
  k_project<<<(N_NODES + 15) / 16, 256, 0, stream>>>(x, wt, bl, Y, OUTI);
  k_gather<<<N_NODES / 4, 384, 0, stream>>>(Y, OUTI, rowptr, col, header, linW, linb, sbuf);
  k_pmax<<<64, 256, 0, stream>>>(sbuf, pmax);
  k_fmax<<<1, 64, 0, stream>>>(pmax, header);
  k_exps<<<64, 256, 0, stream>>>(sbuf, header, out, psum);
  k_fsum<<<1, 64, 0, stream>>>(psum, header);
  k_scale<<<(N_NODES + 255) / 256, 256, 0, stream>>>(out, header);
}